// Round 10
// baseline (222.003 us; speedup 1.0000x reference)
//
#include <hip/hip_runtime.h>

#define N_NODES  50000
#define N_EDGES  800000
#define N_GRAPHS 512
#define HID      64
#define NCLS     5
#define NB       64      // bucket capacity per node (max deg ~40 for this graph)
#define EST      36      // LDS embed row stride in uints (36*4=144B: bank-swizzled, 16B-aligned)

typedef __attribute__((ext_vector_type(8))) short bf16x8;
typedef __attribute__((ext_vector_type(4))) float f32x4;

__device__ inline unsigned short f2bf(float f) {
    unsigned int u = __builtin_bit_cast(unsigned int, f);
    unsigned int r = (u + 0x7FFFu + ((u >> 16) & 1u)) >> 16;   // RNE
    return (unsigned short)r;
}
__device__ inline unsigned int packbf(float a, float b) {
    return (unsigned int)f2bf(a) | ((unsigned int)f2bf(b) << 16);
}
__device__ inline float bf2f(unsigned int u16) {
    unsigned int t = u16 << 16;
    return __builtin_bit_cast(float, t);
}

// ------- fused prep+fill: embed-pack | batch boundaries | pack W1/W2 | bucket fill -------
#define EBUF_T (128 * 32)
#define PW_T   (64 * 64)
#define PREP_T (EBUF_T + N_NODES + 2 * PW_T + N_EDGES)
__global__ void k_prep_fill(
    const float* __restrict__ embed, unsigned int* __restrict__ ebufg,
    const int* __restrict__ batch,
    int* __restrict__ pos_start, int* __restrict__ pos_end,
    const float* __restrict__ W1l, const float* __restrict__ W1r,
    unsigned int* __restrict__ wb1,
    const float* __restrict__ W2l, const float* __restrict__ W2r,
    unsigned int* __restrict__ wb2,
    const int* __restrict__ src, const int* __restrict__ dst,
    int* __restrict__ cnt, unsigned short* __restrict__ bucket) {
    int gid = blockIdx.x * blockDim.x + threadIdx.x;
    if (gid < EBUF_T) {
        int t = gid >> 5, c = gid & 31;
        float2 v = ((const float2*)(embed + (long)t * HID))[c];
        ebufg[gid] = packbf(v.x, v.y);
        return;
    }
    gid -= EBUF_T;
    if (gid < N_NODES) {
        int n = gid;
        int b = batch[n];
        if (n == 0 || batch[n - 1] != b) pos_start[b] = n;
        if (n == N_NODES - 1 || batch[n + 1] != b) pos_end[b] = n + 1;
        return;
    }
    gid -= N_NODES;
    if (gid < 2 * PW_T) {
        const float* Wl = (gid < PW_T) ? W1l : W2l;
        const float* Wr = (gid < PW_T) ? W1r : W2r;
        unsigned int* wb = (gid < PW_T) ? wb1 : wb2;
        int i = (gid < PW_T) ? gid : gid - PW_T;
        int h = i >> 6, c = i & 63;   // row h: uints 0..31 = Wl, 32..63 = Wr
        float2 v = (c < 32) ? ((const float2*)(Wl + (long)h * HID))[c]
                            : ((const float2*)(Wr + (long)h * HID))[c - 32];
        wb[i] = packbf(v.x, v.y);
        return;
    }
    gid -= 2 * PW_T;
    if (gid < N_EDGES) {
        int s = src[gid], d = dst[gid];
        int pos = atomicAdd(&cnt[d], 1);
        if (pos < NB) bucket[(long)d * NB + pos] = (unsigned short)s;
    }
}

// ------- layer-1 aggregation: bucket(src) -> tok gather -> LDS embedding table -------
__global__ __launch_bounds__(256) void k_agg1(
    const int* __restrict__ cnt, const unsigned short* __restrict__ bucket,
    const int* __restrict__ tok,
    const unsigned int* __restrict__ ebufg, unsigned int* __restrict__ aggb) {
    __shared__ unsigned int elds[128 * EST];
    const int tid = threadIdx.x;
    for (int i = tid; i < EBUF_T; i += 256) {
        int t = i >> 5, c = i & 31;
        elds[t * EST + c] = ebufg[i];
    }
    __syncthreads();

    int n    = (blockIdx.x * 256 + tid) >> 6;   // grid exact multiple
    int lane = tid & 63;
    int q    = lane & 7;
    int e8   = lane >> 3;
    int deg  = cnt[n];
    int m    = min(deg, NB);
    unsigned int v = (lane < m) ? (unsigned int)bucket[(long)n * NB + lane] : 0u;
    float f0 = 0, f1 = 0, f2 = 0, f3 = 0, f4 = 0, f5 = 0, f6 = 0, f7 = 0;
#pragma unroll
    for (int g = 0; g < 8; ++g) {
        int j = g * 8 + e8;
        unsigned int s = __shfl(v, j, 64);
        if (j < m) {
            int tk = tok[s];
            uint4 w = *((const uint4*)(elds + tk * EST + q * 4));
            f0 += bf2f(w.x & 0xffff); f1 += bf2f(w.x >> 16);
            f2 += bf2f(w.y & 0xffff); f3 += bf2f(w.y >> 16);
            f4 += bf2f(w.z & 0xffff); f5 += bf2f(w.z >> 16);
            f6 += bf2f(w.w & 0xffff); f7 += bf2f(w.w >> 16);
        }
    }
#pragma unroll
    for (int o = 8; o < 64; o <<= 1) {
        f0 += __shfl_xor(f0, o, 64); f1 += __shfl_xor(f1, o, 64);
        f2 += __shfl_xor(f2, o, 64); f3 += __shfl_xor(f3, o, 64);
        f4 += __shfl_xor(f4, o, 64); f5 += __shfl_xor(f5, o, 64);
        f6 += __shfl_xor(f6, o, 64); f7 += __shfl_xor(f7, o, 64);
    }
    if (e8 == 0) {
        float inv = 1.0f / (float)max(deg, 1);
        uint4 o;
        o.x = packbf(f0 * inv, f1 * inv);
        o.y = packbf(f2 * inv, f3 * inv);
        o.z = packbf(f4 * inv, f5 * inv);
        o.w = packbf(f6 * inv, f7 * inv);
        *((uint4*)(aggb + (long)n * 32) + q) = o;
    }
}

// ------- layer-2 aggregation: bucket(src) -> global gather of x1 -------
__global__ __launch_bounds__(256) void k_agg2(
    const int* __restrict__ cnt, const unsigned short* __restrict__ bucket,
    const unsigned int* __restrict__ xb, unsigned int* __restrict__ aggb) {
    const int tid = threadIdx.x;
    int n    = (blockIdx.x * 256 + tid) >> 6;
    int lane = tid & 63;
    int q    = lane & 7;
    int e8   = lane >> 3;
    int deg  = cnt[n];
    int m    = min(deg, NB);
    unsigned int v = (lane < m) ? (unsigned int)bucket[(long)n * NB + lane] : 0u;
    float f0 = 0, f1 = 0, f2 = 0, f3 = 0, f4 = 0, f5 = 0, f6 = 0, f7 = 0;
#pragma unroll
    for (int g = 0; g < 8; ++g) {
        int j = g * 8 + e8;
        unsigned int s = __shfl(v, j, 64);
        if (j < m) {
            uint4 w = *((const uint4*)(xb + (long)s * 32) + q);
            f0 += bf2f(w.x & 0xffff); f1 += bf2f(w.x >> 16);
            f2 += bf2f(w.y & 0xffff); f3 += bf2f(w.y >> 16);
            f4 += bf2f(w.z & 0xffff); f5 += bf2f(w.z >> 16);
            f6 += bf2f(w.w & 0xffff); f7 += bf2f(w.w >> 16);
        }
    }
#pragma unroll
    for (int o = 8; o < 64; o <<= 1) {
        f0 += __shfl_xor(f0, o, 64); f1 += __shfl_xor(f1, o, 64);
        f2 += __shfl_xor(f2, o, 64); f3 += __shfl_xor(f3, o, 64);
        f4 += __shfl_xor(f4, o, 64); f5 += __shfl_xor(f5, o, 64);
        f6 += __shfl_xor(f6, o, 64); f7 += __shfl_xor(f7, o, 64);
    }
    if (e8 == 0) {
        float inv = 1.0f / (float)max(deg, 1);
        uint4 o;
        o.x = packbf(f0 * inv, f1 * inv);
        o.y = packbf(f2 * inv, f3 * inv);
        o.z = packbf(f4 * inv, f5 * inv);
        o.w = packbf(f6 * inv, f7 * inv);
        *((uint4*)(aggb + (long)n * 32) + q) = o;
    }
}

// ---------------- transform: zero-LDS MFMA, atomic-free ----------------
// out[n][h] = relu( [agg | x_self] @ [Wl|Wr]^T + bl ), K=128 bf16.
// Swapped operands -> C^T layout: lane m = node, regs = 4 consecutive h ->
// ushort4 stores completing full 128B lines per wave.
__global__ __launch_bounds__(256) void k_transform(
    const unsigned int* __restrict__ aggb, const unsigned int* __restrict__ xsrc,
    const int* __restrict__ tok,   // nullptr for layer 2
    const unsigned int* __restrict__ wb, const float* __restrict__ bl,
    unsigned short* __restrict__ xoutb)
{
    const int tid  = threadIdx.x;
    const int lane = tid & 63;
    const int w    = tid >> 6;
    const int nb   = blockIdx.x * 64 + w * 16;
    const int m    = lane & 15;
    const int quad = lane >> 4;

    int row  = nb + m;
    int rowc = min(row, N_NODES - 1);
    const unsigned int* selfp = tok ? (xsrc + (long)tok[rowc] * 32)
                                    : (xsrc + (long)rowc * 32);

    bf16x8 afr[4];
    afr[0] = *(const bf16x8*)(aggb + (long)rowc * 32 + quad * 4);
    afr[1] = *(const bf16x8*)(aggb + (long)rowc * 32 + 16 + quad * 4);
    afr[2] = *(const bf16x8*)(selfp + quad * 4);
    afr[3] = *(const bf16x8*)(selfp + 16 + quad * 4);

    f32x4 acc[4];
#pragma unroll
    for (int t = 0; t < 4; ++t) {
        acc[t] = (f32x4){0.f, 0.f, 0.f, 0.f};
#pragma unroll
        for (int kst = 0; kst < 4; ++kst) {
            bf16x8 bfr = *(const bf16x8*)(wb + (t * 16 + m) * 64 + kst * 16 + quad * 4);
            acc[t] = __builtin_amdgcn_mfma_f32_16x16x32_bf16(bfr, afr[kst], acc[t], 0, 0, 0);
        }
    }

    // C^T[h][node]: h = t*16 + quad*4 + r, node = nb + m
    int node = nb + m;
    if (node < N_NODES) {
#pragma unroll
        for (int t = 0; t < 4; ++t) {
            int hb = t * 16 + quad * 4;
            float4 bb = *(const float4*)(bl + hb);
            ushort4 o;
            o.x = f2bf(fmaxf(acc[t][0] + bb.x, 0.f));
            o.y = f2bf(fmaxf(acc[t][1] + bb.y, 0.f));
            o.z = f2bf(fmaxf(acc[t][2] + bb.z, 0.f));
            o.w = f2bf(fmaxf(acc[t][3] + bb.w, 0.f));
            *(ushort4*)(xoutb + (long)node * HID + hb) = o;
        }
    }
}

// ------- pool + head: one wave per graph; batch sorted -> contiguous node range -------
__global__ __launch_bounds__(64) void k_pool(
    const unsigned int* __restrict__ x2b,
    const int* __restrict__ pos_start, const int* __restrict__ pos_end,
    const float* __restrict__ Wlin, const float* __restrict__ blin,
    float* __restrict__ out)
{
    int g    = blockIdx.x;
    int lane = threadIdx.x;
    int q    = lane & 7;     // 16B chunk (channels 8q..8q+7)
    int slot = lane >> 3;    // node slot within group of 8
    int s = pos_start[g], e = pos_end[g];
    float f0 = 0, f1 = 0, f2 = 0, f3 = 0, f4 = 0, f5 = 0, f6 = 0, f7 = 0;
    for (int n = s + slot; n < e; n += 8) {
        uint4 v = *((const uint4*)(x2b + (long)n * 32) + q);
        f0 += bf2f(v.x & 0xffff); f1 += bf2f(v.x >> 16);
        f2 += bf2f(v.y & 0xffff); f3 += bf2f(v.y >> 16);
        f4 += bf2f(v.z & 0xffff); f5 += bf2f(v.z >> 16);
        f6 += bf2f(v.w & 0xffff); f7 += bf2f(v.w >> 16);
    }
#pragma unroll
    for (int o = 8; o < 64; o <<= 1) {
        f0 += __shfl_xor(f0, o, 64); f1 += __shfl_xor(f1, o, 64);
        f2 += __shfl_xor(f2, o, 64); f3 += __shfl_xor(f3, o, 64);
        f4 += __shfl_xor(f4, o, 64); f5 += __shfl_xor(f5, o, 64);
        f6 += __shfl_xor(f6, o, 64); f7 += __shfl_xor(f7, o, 64);
    }
    float inv = 1.0f / (float)max(e - s, 1);
    f0 *= inv; f1 *= inv; f2 *= inv; f3 *= inv;
    f4 *= inv; f5 *= inv; f6 *= inv; f7 *= inv;
#pragma unroll
    for (int c = 0; c < NCLS; ++c) {
        const float* wr = Wlin + c * HID + q * 8;
        float p = f0 * wr[0] + f1 * wr[1] + f2 * wr[2] + f3 * wr[3] +
                  f4 * wr[4] + f5 * wr[5] + f6 * wr[6] + f7 * wr[7];
        p += __shfl_xor(p, 1, 64);
        p += __shfl_xor(p, 2, 64);
        p += __shfl_xor(p, 4, 64);
        if (lane == 0) out[g * NCLS + c] = p + blin[c];
    }
}

extern "C" void kernel_launch(void* const* d_in, const int* in_sizes, int n_in,
                              void* d_out, int out_size, void* d_ws, size_t ws_size,
                              hipStream_t stream) {
    const int*   tok   = (const int*)d_in[0];
    const int*   eidx  = (const int*)d_in[1];
    const int*   batch = (const int*)d_in[2];
    const float* embed = (const float*)d_in[3];
    const float* W1l   = (const float*)d_in[4];
    const float* b1l   = (const float*)d_in[5];
    const float* W1r   = (const float*)d_in[6];
    const float* W2l   = (const float*)d_in[7];
    const float* b2l   = (const float*)d_in[8];
    const float* W2r   = (const float*)d_in[9];
    const float* Wlin  = (const float*)d_in[10];
    const float* blin  = (const float*)d_in[11];
    float* out = (float*)d_out;

    const int* src = eidx;
    const int* dst = eidx + N_EDGES;

    char* wsp = (char*)d_ws;
    size_t off = 0;
    auto alloc = [&](size_t bytes) -> void* {
        void* p = wsp + off;
        off = (off + bytes + 255) & ~(size_t)255;
        return p;
    };
    // cnt | pstart | pend adjacent -> single memset
    int*   cnt     = (int*)  alloc((size_t)N_NODES * 4);
    int*   pstart  = (int*)  alloc((size_t)N_GRAPHS * 4);
    int*   pend    = (int*)  alloc((size_t)N_GRAPHS * 4);
    unsigned short* bucket = (unsigned short*)alloc((size_t)N_NODES * NB * 2);
    unsigned int* aggb   = (unsigned int*)alloc((size_t)N_NODES * 32 * 4);
    unsigned int* x1b    = (unsigned int*)alloc((size_t)N_NODES * 32 * 4);
    unsigned int* x2b    = (unsigned int*)alloc((size_t)N_NODES * 32 * 4);
    unsigned int* ebufg  = (unsigned int*)alloc((size_t)128 * 32 * 4);
    unsigned int* wb1    = (unsigned int*)alloc((size_t)64 * 64 * 4);
    unsigned int* wb2    = (unsigned int*)alloc((size_t)64 * 64 * 4);

    hipMemsetAsync(cnt, 0, (char*)pend - (char*)cnt + (size_t)N_GRAPHS * 4, stream);

    k_prep_fill<<<(PREP_T + 255) / 256, 256, 0, stream>>>(
        embed, ebufg, batch, pstart, pend, W1l, W1r, wb1, W2l, W2r, wb2,
        src, dst, cnt, bucket);

    const int ABLK = (N_NODES * 64) / 256;   // exact
    const int TBLK = (N_NODES + 63) / 64;
    // Layer 1 (embedding table in LDS; self term from ebuf via tok)
    k_agg1<<<ABLK, 256, 0, stream>>>(cnt, bucket, tok, ebufg, aggb);
    k_transform<<<TBLK, 256, 0, stream>>>(aggb, ebufg, tok, wb1, b1l,
                                          (unsigned short*)x1b);
    // Layer 2
    k_agg2<<<ABLK, 256, 0, stream>>>(cnt, bucket, x1b, aggb);
    k_transform<<<TBLK, 256, 0, stream>>>(aggb, x1b, nullptr, wb2, b2l,
                                          (unsigned short*)x2b);

    // Pool + head
    k_pool<<<N_GRAPHS, 64, 0, stream>>>(x2b, pstart, pend, Wlin, blin, out);
}

// Round 11
// 215.799 us; speedup vs baseline: 1.0287x; 1.0287x over previous
//
#include <hip/hip_runtime.h>

#define N_NODES  50000
#define N_EDGES  800000
#define N_GRAPHS 512
#define HID      64
#define NCLS     5
#define NB       64      // bucket capacity per node (max deg ~40 for this graph)
#define EST      36      // LDS embed row stride in uints (36*4=144B: bank-swizzled, 16B-aligned)
#define FILL_GB  128     // blocks per XCD-group in k_fill

typedef __attribute__((ext_vector_type(8))) short bf16x8;
typedef __attribute__((ext_vector_type(4))) float f32x4;

__device__ inline unsigned short f2bf(float f) {
    unsigned int u = __builtin_bit_cast(unsigned int, f);
    unsigned int r = (u + 0x7FFFu + ((u >> 16) & 1u)) >> 16;   // RNE
    return (unsigned short)r;
}
__device__ inline unsigned int packbf(float a, float b) {
    return (unsigned int)f2bf(a) | ((unsigned int)f2bf(b) << 16);
}
__device__ inline float bf2f(unsigned int u16) {
    unsigned int t = u16 << 16;
    return __builtin_bit_cast(float, t);
}

// ------- prep: embed-pack | batch boundaries | pack W1/W2 | edge-pack -------
#define EBUF_T (128 * 32)
#define PW_T   (64 * 64)
#define PREP_T (EBUF_T + N_NODES + 2 * PW_T + N_EDGES)
__global__ void k_prep(
    const float* __restrict__ embed, unsigned int* __restrict__ ebufg,
    const int* __restrict__ batch,
    int* __restrict__ pos_start, int* __restrict__ pos_end,
    const float* __restrict__ W1l, const float* __restrict__ W1r,
    unsigned int* __restrict__ wb1,
    const float* __restrict__ W2l, const float* __restrict__ W2r,
    unsigned int* __restrict__ wb2,
    const int* __restrict__ src, const int* __restrict__ dst,
    const int* __restrict__ tok, uint2* __restrict__ epack) {
    int gid = blockIdx.x * blockDim.x + threadIdx.x;
    if (gid < EBUF_T) {
        int t = gid >> 5, c = gid & 31;
        float2 v = ((const float2*)(embed + (long)t * HID))[c];
        ebufg[gid] = packbf(v.x, v.y);
        return;
    }
    gid -= EBUF_T;
    if (gid < N_NODES) {
        int n = gid;
        int b = batch[n];
        if (n == 0 || batch[n - 1] != b) pos_start[b] = n;
        if (n == N_NODES - 1 || batch[n + 1] != b) pos_end[b] = n + 1;
        return;
    }
    gid -= N_NODES;
    if (gid < 2 * PW_T) {
        const float* Wl = (gid < PW_T) ? W1l : W2l;
        const float* Wr = (gid < PW_T) ? W1r : W2r;
        unsigned int* wb = (gid < PW_T) ? wb1 : wb2;
        int i = (gid < PW_T) ? gid : gid - PW_T;
        int h = i >> 6, c = i & 63;   // row h: uints 0..31 = Wl, 32..63 = Wr
        float2 v = (c < 32) ? ((const float2*)(Wl + (long)h * HID))[c]
                            : ((const float2*)(Wr + (long)h * HID))[c - 32];
        wb[i] = packbf(v.x, v.y);
        return;
    }
    gid -= 2 * PW_T;
    if (gid < N_EDGES) {
        int s = src[gid];
        unsigned int t = (unsigned int)tok[s];        // L2-hot 200KB gather
        epack[gid] = make_uint2((unsigned int)s | (t << 16), (unsigned int)dst[gid]);
    }
}

// ------- XCD-partitioned bucket fill: group x handles only dst with (dst&7)==x -------
// blockIdx % 8 ~ XCD (round-robin heuristic): all writes/atomics for a dst stay on
// one XCD -> bucket lines written back once (no cross-XCD sector bouncing).
__global__ __launch_bounds__(256) void k_fill(
    const uint2* __restrict__ epack, int* __restrict__ cnt,
    unsigned int* __restrict__ bucket) {
    const int x  = blockIdx.x & 7;
    const int bs = blockIdx.x >> 3;                    // 0..FILL_GB-1
    for (int e = bs * 256 + threadIdx.x; e < N_EDGES; e += 256 * FILL_GB) {
        uint2 v = epack[e];
        int d = (int)v.y;
        if ((d & 7) == x) {
            int pos = atomicAdd(&cnt[d], 1);
            if (pos < NB) bucket[(long)d * NB + pos] = v.x;
        }
    }
}

// ------- layer-1 aggregation: bucket(tok<<16|src) -> LDS embedding table -------
__global__ __launch_bounds__(256) void k_agg1(
    const int* __restrict__ cnt, const unsigned int* __restrict__ bucket,
    const unsigned int* __restrict__ ebufg, unsigned int* __restrict__ aggb) {
    __shared__ unsigned int elds[128 * EST];
    const int tid = threadIdx.x;
    for (int i = tid; i < EBUF_T; i += 256) {
        int t = i >> 5, c = i & 31;
        elds[t * EST + c] = ebufg[i];
    }
    __syncthreads();

    int n    = (blockIdx.x * 256 + tid) >> 6;   // grid exact multiple
    int lane = tid & 63;
    int q    = lane & 7;
    int e8   = lane >> 3;
    int deg  = cnt[n];
    int m    = min(deg, NB);
    unsigned int v = (lane < m) ? bucket[(long)n * NB + lane] : 0u;
    float f0 = 0, f1 = 0, f2 = 0, f3 = 0, f4 = 0, f5 = 0, f6 = 0, f7 = 0;
#pragma unroll
    for (int g = 0; g < 8; ++g) {
        int j = g * 8 + e8;
        unsigned int vv = __shfl(v, j, 64);
        if (j < m) {
            int tk = (int)(vv >> 16);
            uint4 w = *((const uint4*)(elds + tk * EST + q * 4));
            f0 += bf2f(w.x & 0xffff); f1 += bf2f(w.x >> 16);
            f2 += bf2f(w.y & 0xffff); f3 += bf2f(w.y >> 16);
            f4 += bf2f(w.z & 0xffff); f5 += bf2f(w.z >> 16);
            f6 += bf2f(w.w & 0xffff); f7 += bf2f(w.w >> 16);
        }
    }
#pragma unroll
    for (int o = 8; o < 64; o <<= 1) {
        f0 += __shfl_xor(f0, o, 64); f1 += __shfl_xor(f1, o, 64);
        f2 += __shfl_xor(f2, o, 64); f3 += __shfl_xor(f3, o, 64);
        f4 += __shfl_xor(f4, o, 64); f5 += __shfl_xor(f5, o, 64);
        f6 += __shfl_xor(f6, o, 64); f7 += __shfl_xor(f7, o, 64);
    }
    if (e8 == 0) {
        float inv = 1.0f / (float)max(deg, 1);
        uint4 o;
        o.x = packbf(f0 * inv, f1 * inv);
        o.y = packbf(f2 * inv, f3 * inv);
        o.z = packbf(f4 * inv, f5 * inv);
        o.w = packbf(f6 * inv, f7 * inv);
        *((uint4*)(aggb + (long)n * 32) + q) = o;
    }
}

// ------- layer-2 aggregation: bucket(src) -> global gather of x1 -------
__global__ __launch_bounds__(256) void k_agg2(
    const int* __restrict__ cnt, const unsigned int* __restrict__ bucket,
    const unsigned int* __restrict__ xb, unsigned int* __restrict__ aggb) {
    const int tid = threadIdx.x;
    int n    = (blockIdx.x * 256 + tid) >> 6;
    int lane = tid & 63;
    int q    = lane & 7;
    int e8   = lane >> 3;
    int deg  = cnt[n];
    int m    = min(deg, NB);
    unsigned int v = (lane < m) ? bucket[(long)n * NB + lane] : 0u;
    float f0 = 0, f1 = 0, f2 = 0, f3 = 0, f4 = 0, f5 = 0, f6 = 0, f7 = 0;
#pragma unroll
    for (int g = 0; g < 8; ++g) {
        int j = g * 8 + e8;
        unsigned int vv = __shfl(v, j, 64);
        if (j < m) {
            int s = (int)(vv & 0xffffu);
            uint4 w = *((const uint4*)(xb + (long)s * 32) + q);
            f0 += bf2f(w.x & 0xffff); f1 += bf2f(w.x >> 16);
            f2 += bf2f(w.y & 0xffff); f3 += bf2f(w.y >> 16);
            f4 += bf2f(w.z & 0xffff); f5 += bf2f(w.z >> 16);
            f6 += bf2f(w.w & 0xffff); f7 += bf2f(w.w >> 16);
        }
    }
#pragma unroll
    for (int o = 8; o < 64; o <<= 1) {
        f0 += __shfl_xor(f0, o, 64); f1 += __shfl_xor(f1, o, 64);
        f2 += __shfl_xor(f2, o, 64); f3 += __shfl_xor(f3, o, 64);
        f4 += __shfl_xor(f4, o, 64); f5 += __shfl_xor(f5, o, 64);
        f6 += __shfl_xor(f6, o, 64); f7 += __shfl_xor(f7, o, 64);
    }
    if (e8 == 0) {
        float inv = 1.0f / (float)max(deg, 1);
        uint4 o;
        o.x = packbf(f0 * inv, f1 * inv);
        o.y = packbf(f2 * inv, f3 * inv);
        o.z = packbf(f4 * inv, f5 * inv);
        o.w = packbf(f6 * inv, f7 * inv);
        *((uint4*)(aggb + (long)n * 32) + q) = o;
    }
}

// ---------------- transform: zero-LDS MFMA, atomic-free ----------------
// out[n][h] = relu( [agg | x_self] @ [Wl|Wr]^T + bl ), K=128 bf16.
// Swapped operands -> C^T layout: lane m = node, regs = 4 consecutive h ->
// ushort4 stores completing full 128B lines per wave.
__global__ __launch_bounds__(256) void k_transform(
    const unsigned int* __restrict__ aggb, const unsigned int* __restrict__ xsrc,
    const int* __restrict__ tok,   // nullptr for layer 2
    const unsigned int* __restrict__ wb, const float* __restrict__ bl,
    unsigned short* __restrict__ xoutb)
{
    const int tid  = threadIdx.x;
    const int lane = tid & 63;
    const int w    = tid >> 6;
    const int nb   = blockIdx.x * 64 + w * 16;
    const int m    = lane & 15;
    const int quad = lane >> 4;

    int row  = nb + m;
    int rowc = min(row, N_NODES - 1);
    const unsigned int* selfp = tok ? (xsrc + (long)tok[rowc] * 32)
                                    : (xsrc + (long)rowc * 32);

    bf16x8 afr[4];
    afr[0] = *(const bf16x8*)(aggb + (long)rowc * 32 + quad * 4);
    afr[1] = *(const bf16x8*)(aggb + (long)rowc * 32 + 16 + quad * 4);
    afr[2] = *(const bf16x8*)(selfp + quad * 4);
    afr[3] = *(const bf16x8*)(selfp + 16 + quad * 4);

    f32x4 acc[4];
#pragma unroll
    for (int t = 0; t < 4; ++t) {
        acc[t] = (f32x4){0.f, 0.f, 0.f, 0.f};
#pragma unroll
        for (int kst = 0; kst < 4; ++kst) {
            bf16x8 bfr = *(const bf16x8*)(wb + (t * 16 + m) * 64 + kst * 16 + quad * 4);
            acc[t] = __builtin_amdgcn_mfma_f32_16x16x32_bf16(bfr, afr[kst], acc[t], 0, 0, 0);
        }
    }

    // C^T[h][node]: h = t*16 + quad*4 + r, node = nb + m
    int node = nb + m;
    if (node < N_NODES) {
#pragma unroll
        for (int t = 0; t < 4; ++t) {
            int hb = t * 16 + quad * 4;
            float4 bb = *(const float4*)(bl + hb);
            ushort4 o;
            o.x = f2bf(fmaxf(acc[t][0] + bb.x, 0.f));
            o.y = f2bf(fmaxf(acc[t][1] + bb.y, 0.f));
            o.z = f2bf(fmaxf(acc[t][2] + bb.z, 0.f));
            o.w = f2bf(fmaxf(acc[t][3] + bb.w, 0.f));
            *(ushort4*)(xoutb + (long)node * HID + hb) = o;
        }
    }
}

// ------- pool + head: one wave per graph; batch sorted -> contiguous node range -------
__global__ __launch_bounds__(64) void k_pool(
    const unsigned int* __restrict__ x2b,
    const int* __restrict__ pos_start, const int* __restrict__ pos_end,
    const float* __restrict__ Wlin, const float* __restrict__ blin,
    float* __restrict__ out)
{
    int g    = blockIdx.x;
    int lane = threadIdx.x;
    int q    = lane & 7;     // 16B chunk (channels 8q..8q+7)
    int slot = lane >> 3;    // node slot within group of 8
    int s = pos_start[g], e = pos_end[g];
    float f0 = 0, f1 = 0, f2 = 0, f3 = 0, f4 = 0, f5 = 0, f6 = 0, f7 = 0;
    for (int n = s + slot; n < e; n += 8) {
        uint4 v = *((const uint4*)(x2b + (long)n * 32) + q);
        f0 += bf2f(v.x & 0xffff); f1 += bf2f(v.x >> 16);
        f2 += bf2f(v.y & 0xffff); f3 += bf2f(v.y >> 16);
        f4 += bf2f(v.z & 0xffff); f5 += bf2f(v.z >> 16);
        f6 += bf2f(v.w & 0xffff); f7 += bf2f(v.w >> 16);
    }
#pragma unroll
    for (int o = 8; o < 64; o <<= 1) {
        f0 += __shfl_xor(f0, o, 64); f1 += __shfl_xor(f1, o, 64);
        f2 += __shfl_xor(f2, o, 64); f3 += __shfl_xor(f3, o, 64);
        f4 += __shfl_xor(f4, o, 64); f5 += __shfl_xor(f5, o, 64);
        f6 += __shfl_xor(f6, o, 64); f7 += __shfl_xor(f7, o, 64);
    }
    float inv = 1.0f / (float)max(e - s, 1);
    f0 *= inv; f1 *= inv; f2 *= inv; f3 *= inv;
    f4 *= inv; f5 *= inv; f6 *= inv; f7 *= inv;
#pragma unroll
    for (int c = 0; c < NCLS; ++c) {
        const float* wr = Wlin + c * HID + q * 8;
        float p = f0 * wr[0] + f1 * wr[1] + f2 * wr[2] + f3 * wr[3] +
                  f4 * wr[4] + f5 * wr[5] + f6 * wr[6] + f7 * wr[7];
        p += __shfl_xor(p, 1, 64);
        p += __shfl_xor(p, 2, 64);
        p += __shfl_xor(p, 4, 64);
        if (lane == 0) out[g * NCLS + c] = p + blin[c];
    }
}

extern "C" void kernel_launch(void* const* d_in, const int* in_sizes, int n_in,
                              void* d_out, int out_size, void* d_ws, size_t ws_size,
                              hipStream_t stream) {
    const int*   tok   = (const int*)d_in[0];
    const int*   eidx  = (const int*)d_in[1];
    const int*   batch = (const int*)d_in[2];
    const float* embed = (const float*)d_in[3];
    const float* W1l   = (const float*)d_in[4];
    const float* b1l   = (const float*)d_in[5];
    const float* W1r   = (const float*)d_in[6];
    const float* W2l   = (const float*)d_in[7];
    const float* b2l   = (const float*)d_in[8];
    const float* W2r   = (const float*)d_in[9];
    const float* Wlin  = (const float*)d_in[10];
    const float* blin  = (const float*)d_in[11];
    float* out = (float*)d_out;

    const int* src = eidx;
    const int* dst = eidx + N_EDGES;

    char* wsp = (char*)d_ws;
    size_t off = 0;
    auto alloc = [&](size_t bytes) -> void* {
        void* p = wsp + off;
        off = (off + bytes + 255) & ~(size_t)255;
        return p;
    };
    // cnt | pstart | pend adjacent -> single memset
    int*   cnt     = (int*)  alloc((size_t)N_NODES * 4);
    int*   pstart  = (int*)  alloc((size_t)N_GRAPHS * 4);
    int*   pend    = (int*)  alloc((size_t)N_GRAPHS * 4);
    unsigned int* bucket = (unsigned int*)alloc((size_t)N_NODES * NB * 4);
    uint2* epack         = (uint2*)alloc((size_t)N_EDGES * 8);
    unsigned int* aggb   = (unsigned int*)alloc((size_t)N_NODES * 32 * 4);
    unsigned int* x1b    = (unsigned int*)alloc((size_t)N_NODES * 32 * 4);
    unsigned int* x2b    = (unsigned int*)alloc((size_t)N_NODES * 32 * 4);
    unsigned int* ebufg  = (unsigned int*)alloc((size_t)128 * 32 * 4);
    unsigned int* wb1    = (unsigned int*)alloc((size_t)64 * 64 * 4);
    unsigned int* wb2    = (unsigned int*)alloc((size_t)64 * 64 * 4);

    hipMemsetAsync(cnt, 0, (char*)pend - (char*)cnt + (size_t)N_GRAPHS * 4, stream);

    k_prep<<<(PREP_T + 255) / 256, 256, 0, stream>>>(
        embed, ebufg, batch, pstart, pend, W1l, W1r, wb1, W2l, W2r, wb2,
        src, dst, tok, epack);

    k_fill<<<8 * FILL_GB, 256, 0, stream>>>(epack, cnt, bucket);

    const int ABLK = (N_NODES * 64) / 256;   // exact
    const int TBLK = (N_NODES + 63) / 64;
    // Layer 1 (embedding table in LDS; self term from ebuf via tok)
    k_agg1<<<ABLK, 256, 0, stream>>>(cnt, bucket, ebufg, aggb);
    k_transform<<<TBLK, 256, 0, stream>>>(aggb, ebufg, tok, wb1, b1l,
                                          (unsigned short*)x1b);
    // Layer 2
    k_agg2<<<ABLK, 256, 0, stream>>>(cnt, bucket, x1b, aggb);
    k_transform<<<TBLK, 256, 0, stream>>>(aggb, x1b, nullptr, wb2, b2l,
                                          (unsigned short*)x2b);

    // Pool + head
    k_pool<<<N_GRAPHS, 64, 0, stream>>>(x2b, pstart, pend, Wlin, blin, out);
}

// Round 12
// 208.578 us; speedup vs baseline: 1.0644x; 1.0346x over previous
//
#include <hip/hip_runtime.h>

#define N_NODES  50000
#define N_EDGES  800000
#define N_GRAPHS 512
#define HID      64
#define NCLS     5
#define NB       64      // bucket capacity per node (max deg ~40 for this graph)
#define EST      36      // LDS embed row stride in uints
#define AST      68      // LDS As row stride in uints (64 data + 4 pad)

typedef __attribute__((ext_vector_type(8))) short bf16x8;
typedef __attribute__((ext_vector_type(4))) float f32x4;

__device__ inline unsigned short f2bf(float f) {
    unsigned int u = __builtin_bit_cast(unsigned int, f);
    unsigned int r = (u + 0x7FFFu + ((u >> 16) & 1u)) >> 16;   // RNE
    return (unsigned short)r;
}
__device__ inline unsigned int packbf(float a, float b) {
    return (unsigned int)f2bf(a) | ((unsigned int)f2bf(b) << 16);
}
__device__ inline float bf2f(unsigned int u16) {
    unsigned int t = u16 << 16;
    return __builtin_bit_cast(float, t);
}

// ------- prep: embed-pack | batch boundaries | pack W1/W2 (R9 version) -------
#define EBUF_T (128 * 32)
#define PW_T   (64 * 64)
#define PREP_T (EBUF_T + N_NODES + 2 * PW_T)
__global__ void k_prep(
    const float* __restrict__ embed, unsigned int* __restrict__ ebufg,
    const int* __restrict__ batch,
    int* __restrict__ pos_start, int* __restrict__ pos_end,
    const float* __restrict__ W1l, const float* __restrict__ W1r,
    unsigned int* __restrict__ wb1,
    const float* __restrict__ W2l, const float* __restrict__ W2r,
    unsigned int* __restrict__ wb2) {
    int gid = blockIdx.x * blockDim.x + threadIdx.x;
    if (gid < EBUF_T) {
        int t = gid >> 5, c = gid & 31;
        float2 v = ((const float2*)(embed + (long)t * HID))[c];
        ebufg[gid] = packbf(v.x, v.y);
        return;
    }
    gid -= EBUF_T;
    if (gid < N_NODES) {
        int n = gid;
        int b = batch[n];
        if (n == 0 || batch[n - 1] != b) pos_start[b] = n;
        if (n == N_NODES - 1 || batch[n + 1] != b) pos_end[b] = n + 1;
        return;
    }
    gid -= N_NODES;
    if (gid < 2 * PW_T) {
        const float* Wl = (gid < PW_T) ? W1l : W2l;
        const float* Wr = (gid < PW_T) ? W1r : W2r;
        unsigned int* wb = (gid < PW_T) ? wb1 : wb2;
        int i = (gid < PW_T) ? gid : gid - PW_T;
        int h = i >> 6, c = i & 63;   // row h: uints 0..31 = Wl, 32..63 = Wr
        float2 v = (c < 32) ? ((const float2*)(Wl + (long)h * HID))[c]
                            : ((const float2*)(Wr + (long)h * HID))[c - 32];
        wb[i] = packbf(v.x, v.y);
    }
}

// ------- bucket fill (R9 version): cnt atomic + (tok<<16|src) slot store -------
__global__ void k_fill(const int* __restrict__ src, const int* __restrict__ dst,
                       const int* __restrict__ tok,
                       int* __restrict__ cnt, unsigned int* __restrict__ bucket) {
    int e = blockIdx.x * blockDim.x + threadIdx.x;
    if (e >= N_EDGES) return;
    int s = src[e], d = dst[e];
    unsigned int t = (unsigned int)tok[s];             // L2-hot 200KB gather
    int pos = atomicAdd(&cnt[d], 1);
    if (pos < NB) bucket[(long)d * NB + pos] = (unsigned int)s | (t << 16);
}

// ------- fused layer: 1024-thr block = 16 waves = 64 nodes ------------------
// Phase A (full TLP, one wave per node at a time, 4 nodes/wave):
//   gather-mean from bucket -> bf16 row in LDS As[64][AST]; e8==1 lanes stage
//   the self row ([agg | x_self], K=128).
// Phase B (after one barrier): wave w -> node strip (w&3), h-tile (w>>2);
//   4 MFMAs, C^T layout, one ushort4 full-line store per lane.
// L1: neighbor/self features from LDS embed table via tok; L2: from global xb.
template <bool L1>
__global__ __launch_bounds__(1024) void k_layer(
    const int* __restrict__ cnt, const unsigned int* __restrict__ bucket,
    const int* __restrict__ tok, const unsigned int* __restrict__ ebufg,
    const unsigned int* __restrict__ xb,
    const unsigned int* __restrict__ wb, const float* __restrict__ bl,
    unsigned short* __restrict__ xoutb)
{
    __shared__ unsigned int As[64 * AST];
    __shared__ unsigned int elds[L1 ? 128 * EST : 1];
    const int tid  = threadIdx.x;
    const int wv   = tid >> 6;        // 0..15
    const int lane = tid & 63;
    const int n0   = blockIdx.x * 64;

    if (L1) {
        for (int i = tid; i < EBUF_T; i += 1024) {
            int t = i >> 5, c = i & 31;
            elds[t * EST + c] = ebufg[i];
        }
        __syncthreads();
    }

    const int q  = lane & 7;          // 16B chunk (channels 8q..8q+7)
    const int e8 = lane >> 3;         // edge slot within group of 8

#pragma unroll
    for (int i = 0; i < 4; ++i) {
        int rl = wv * 4 + i;          // local row 0..63
        int nn = n0 + rl;
        int nc = min(nn, N_NODES - 1);
        int deg = cnt[nc];
        int m   = (nn < N_NODES) ? min(deg, NB) : 0;
        unsigned int v = (lane < m) ? bucket[(long)nc * NB + lane] : 0u;
        float f0 = 0, f1 = 0, f2 = 0, f3 = 0, f4 = 0, f5 = 0, f6 = 0, f7 = 0;
#pragma unroll
        for (int g = 0; g < 8; ++g) {
            int j = g * 8 + e8;
            unsigned int vv = __shfl(v, j, 64);
            if (j < m) {
                uint4 w4;
                if (L1) w4 = *(const uint4*)(elds + (vv >> 16) * EST + q * 4);
                else    w4 = *((const uint4*)(xb + (long)(vv & 0xffffu) * 32) + q);
                f0 += bf2f(w4.x & 0xffff); f1 += bf2f(w4.x >> 16);
                f2 += bf2f(w4.y & 0xffff); f3 += bf2f(w4.y >> 16);
                f4 += bf2f(w4.z & 0xffff); f5 += bf2f(w4.z >> 16);
                f6 += bf2f(w4.w & 0xffff); f7 += bf2f(w4.w >> 16);
            }
        }
#pragma unroll
        for (int o = 8; o < 64; o <<= 1) {
            f0 += __shfl_xor(f0, o, 64); f1 += __shfl_xor(f1, o, 64);
            f2 += __shfl_xor(f2, o, 64); f3 += __shfl_xor(f3, o, 64);
            f4 += __shfl_xor(f4, o, 64); f5 += __shfl_xor(f5, o, 64);
            f6 += __shfl_xor(f6, o, 64); f7 += __shfl_xor(f7, o, 64);
        }
        if (e8 == 0) {
            float inv = 1.0f / (float)max(deg, 1);
            uint4 o;
            o.x = packbf(f0 * inv, f1 * inv);
            o.y = packbf(f2 * inv, f3 * inv);
            o.z = packbf(f4 * inv, f5 * inv);
            o.w = packbf(f6 * inv, f7 * inv);
            *(uint4*)(As + rl * AST + q * 4) = o;
        } else if (e8 == 1) {
            uint4 sv;
            if (L1) { int tk = tok[nc]; sv = *(const uint4*)(elds + tk * EST + q * 4); }
            else    { sv = *((const uint4*)(xb + (long)nc * 32) + q); }
            *(uint4*)(As + rl * AST + 32 + q * 4) = sv;
        }
    }
    __syncthreads();

    // Phase B: wave wv -> strip s = wv&3 (16 nodes), h-tile t = wv>>2
    const int s    = wv & 3;
    const int t    = wv >> 2;
    const int mm   = lane & 15;
    const int quad = lane >> 4;

    bf16x8 afr[4];
#pragma unroll
    for (int kst = 0; kst < 4; ++kst)
        afr[kst] = *(const bf16x8*)(As + (s * 16 + mm) * AST + kst * 16 + quad * 4);

    f32x4 acc = (f32x4){0.f, 0.f, 0.f, 0.f};
#pragma unroll
    for (int kst = 0; kst < 4; ++kst) {
        bf16x8 bfr = *(const bf16x8*)(wb + (t * 16 + mm) * 64 + kst * 16 + quad * 4);
        acc = __builtin_amdgcn_mfma_f32_16x16x32_bf16(bfr, afr[kst], acc, 0, 0, 0);
    }

    // C^T[h][node]: h = t*16 + quad*4 + r, node = n0 + s*16 + mm
    int node = n0 + s * 16 + mm;
    if (node < N_NODES) {
        int hb = t * 16 + quad * 4;
        float4 bb = *(const float4*)(bl + hb);
        ushort4 o;
        o.x = f2bf(fmaxf(acc[0] + bb.x, 0.f));
        o.y = f2bf(fmaxf(acc[1] + bb.y, 0.f));
        o.z = f2bf(fmaxf(acc[2] + bb.z, 0.f));
        o.w = f2bf(fmaxf(acc[3] + bb.w, 0.f));
        *(ushort4*)(xoutb + (long)node * HID + hb) = o;
    }
}

// ------- pool + head: one wave per graph; batch sorted -> contiguous node range -------
__global__ __launch_bounds__(64) void k_pool(
    const unsigned int* __restrict__ x2b,
    const int* __restrict__ pos_start, const int* __restrict__ pos_end,
    const float* __restrict__ Wlin, const float* __restrict__ blin,
    float* __restrict__ out)
{
    int g    = blockIdx.x;
    int lane = threadIdx.x;
    int q    = lane & 7;     // 16B chunk (channels 8q..8q+7)
    int slot = lane >> 3;    // node slot within group of 8
    int s = pos_start[g], e = pos_end[g];
    float f0 = 0, f1 = 0, f2 = 0, f3 = 0, f4 = 0, f5 = 0, f6 = 0, f7 = 0;
    for (int n = s + slot; n < e; n += 8) {
        uint4 v = *((const uint4*)(x2b + (long)n * 32) + q);
        f0 += bf2f(v.x & 0xffff); f1 += bf2f(v.x >> 16);
        f2 += bf2f(v.y & 0xffff); f3 += bf2f(v.y >> 16);
        f4 += bf2f(v.z & 0xffff); f5 += bf2f(v.z >> 16);
        f6 += bf2f(v.w & 0xffff); f7 += bf2f(v.w >> 16);
    }
#pragma unroll
    for (int o = 8; o < 64; o <<= 1) {
        f0 += __shfl_xor(f0, o, 64); f1 += __shfl_xor(f1, o, 64);
        f2 += __shfl_xor(f2, o, 64); f3 += __shfl_xor(f3, o, 64);
        f4 += __shfl_xor(f4, o, 64); f5 += __shfl_xor(f5, o, 64);
        f6 += __shfl_xor(f6, o, 64); f7 += __shfl_xor(f7, o, 64);
    }
    float inv = 1.0f / (float)max(e - s, 1);
    f0 *= inv; f1 *= inv; f2 *= inv; f3 *= inv;
    f4 *= inv; f5 *= inv; f6 *= inv; f7 *= inv;
#pragma unroll
    for (int c = 0; c < NCLS; ++c) {
        const float* wr = Wlin + c * HID + q * 8;
        float p = f0 * wr[0] + f1 * wr[1] + f2 * wr[2] + f3 * wr[3] +
                  f4 * wr[4] + f5 * wr[5] + f6 * wr[6] + f7 * wr[7];
        p += __shfl_xor(p, 1, 64);
        p += __shfl_xor(p, 2, 64);
        p += __shfl_xor(p, 4, 64);
        if (lane == 0) out[g * NCLS + c] = p + blin[c];
    }
}

extern "C" void kernel_launch(void* const* d_in, const int* in_sizes, int n_in,
                              void* d_out, int out_size, void* d_ws, size_t ws_size,
                              hipStream_t stream) {
    const int*   tok   = (const int*)d_in[0];
    const int*   eidx  = (const int*)d_in[1];
    const int*   batch = (const int*)d_in[2];
    const float* embed = (const float*)d_in[3];
    const float* W1l   = (const float*)d_in[4];
    const float* b1l   = (const float*)d_in[5];
    const float* W1r   = (const float*)d_in[6];
    const float* W2l   = (const float*)d_in[7];
    const float* b2l   = (const float*)d_in[8];
    const float* W2r   = (const float*)d_in[9];
    const float* Wlin  = (const float*)d_in[10];
    const float* blin  = (const float*)d_in[11];
    float* out = (float*)d_out;

    const int* src = eidx;
    const int* dst = eidx + N_EDGES;

    char* wsp = (char*)d_ws;
    size_t off = 0;
    auto alloc = [&](size_t bytes) -> void* {
        void* p = wsp + off;
        off = (off + bytes + 255) & ~(size_t)255;
        return p;
    };
    // cnt | pstart | pend adjacent -> single memset
    int*   cnt     = (int*)  alloc((size_t)N_NODES * 4);
    int*   pstart  = (int*)  alloc((size_t)N_GRAPHS * 4);
    int*   pend    = (int*)  alloc((size_t)N_GRAPHS * 4);
    unsigned int* bucket = (unsigned int*)alloc((size_t)N_NODES * NB * 4);
    unsigned int* x1b    = (unsigned int*)alloc((size_t)N_NODES * 32 * 4);
    unsigned int* x2b    = (unsigned int*)alloc((size_t)N_NODES * 32 * 4);
    unsigned int* ebufg  = (unsigned int*)alloc((size_t)128 * 32 * 4);
    unsigned int* wb1    = (unsigned int*)alloc((size_t)64 * 64 * 4);
    unsigned int* wb2    = (unsigned int*)alloc((size_t)64 * 64 * 4);

    hipMemsetAsync(cnt, 0, (char*)pend - (char*)cnt + (size_t)N_GRAPHS * 4, stream);

    k_prep<<<(PREP_T + 255) / 256, 256, 0, stream>>>(
        embed, ebufg, batch, pstart, pend, W1l, W1r, wb1, W2l, W2r, wb2);

    k_fill<<<(N_EDGES + 255) / 256, 256, 0, stream>>>(src, dst, tok, cnt, bucket);

    const int LBLK = (N_NODES + 63) / 64;
    // Layer 1: neighbors+self from LDS embed table (via tok in bucket / tok[n])
    k_layer<true><<<LBLK, 1024, 0, stream>>>(cnt, bucket, tok, ebufg, nullptr,
                                             wb1, b1l, (unsigned short*)x1b);
    // Layer 2: neighbors+self from x1b
    k_layer<false><<<LBLK, 1024, 0, stream>>>(cnt, bucket, nullptr, nullptr, x1b,
                                              wb2, b2l, (unsigned short*)x2b);

    // Pool + head
    k_pool<<<N_GRAPHS, 64, 0, stream>>>(x2b, pstart, pend, Wlin, blin, out);
}